// Round 2
// baseline (113.275 us; speedup 1.0000x reference)
//
#include <hip/hip_runtime.h>

#define BATCH 4
#define SEQ   512
#define DIM   128

typedef _Float16 half8 __attribute__((ext_vector_type(8)));
typedef _Float16 half4 __attribute__((ext_vector_type(4)));
typedef float    f32x4 __attribute__((ext_vector_type(4)));

static __device__ __forceinline__ half8 cvt_h8(const float4 a, const float4 b) {
    half8 h;
    h[0] = (_Float16)a.x; h[1] = (_Float16)a.y; h[2] = (_Float16)a.z; h[3] = (_Float16)a.w;
    h[4] = (_Float16)b.x; h[5] = (_Float16)b.y; h[6] = (_Float16)b.z; h[7] = (_Float16)b.w;
    return h;
}

// LDS layouts (half elements), XOR-swizzled to break stride-256B bank conflicts:
//   ldsA[m][jj]: m in [0,128) = 2*d_local + {0:ek, 1:ek*v}, jj in [0,128) chunk-j
//   ldsB[t][jj]: t in [0,16) t-tile row, exp(pos) values
#define IDXA(m, jj) ((m) * 128 + ((jj) ^ ((((m) >> 1) & 7) << 3)))
#define IDXB(t, jj) ((t) * 128 + ((jj) ^ (((t) & 7) << 3)))

// ---------------------------------------------------------------------------
// Fully fused AFT: one kernel, zero workspace.
// Grid = 256 blocks = 4 b x 32 t-tiles(16) x 2 d-halves(64). 512 threads.
// Per block, looping over 4 j-chunks of 128:
//   Phase A: proj-T chunk: D[d][j] = sum_k W[d][k] x[j][k]  (A=W rows, B=x rows)
//            epilogue: ldsA[2d][j]=exp(Dk+bk), ldsA[2d+1][j]=exp(.)*(Dv+bv)
//   Phase B: ldsB[t][j] = exp(pos[t][j])  (f16)
//   Phase C: acc += mfma(ldsA rows m, ldsB rows t)  -> num/den accumulate
// Epilogue: q = sigmoid(x[t]. Wq[d] + bq) via f32 VALU dot; out = q*num/den.
// ---------------------------------------------------------------------------
__global__ __launch_bounds__(512, 2) void k_fused(
    const float* __restrict__ x,
    const float* __restrict__ Wq, const float* __restrict__ bq,
    const float* __restrict__ Wk, const float* __restrict__ bk,
    const float* __restrict__ Wv, const float* __restrict__ bv,
    const float* __restrict__ pos,
    float* __restrict__ out)
{
    __shared__ _Float16 ldsA[128 * 128];   // 32 KB
    __shared__ _Float16 ldsB[16 * 128];    // 4 KB

    const int tid  = threadIdx.x;
    const int lane = tid & 63;
    const int w    = tid >> 6;      // wave 0..7
    const int l15  = lane & 15;
    const int quad = lane >> 4;

    const int bid   = blockIdx.x;
    const int b     = bid >> 6;            // batch 0..3
    const int tt    = (bid & 63) >> 1;     // t-tile 0..31
    const int b2    = bid & 1;             // d-half 0..1
    const int t0    = tt * 16;
    const int dbase = b2 * 64;

    // --- phase-A role: wave -> (d-tile, n-half) ---
    const int dt = w & 3;                  // d-tile within the 64-d half
    const int nh = w >> 2;                 // n-half: 4 j-tiles each

    // hoisted W fragments (A-operand rows d = dbase + dt*16 + l15)
    const float* wkr = Wk + (dbase + dt * 16 + l15) * DIM + quad * 8;
    const float* wvr = Wv + (dbase + dt * 16 + l15) * DIM + quad * 8;
    half8 wkf[4], wvf[4];
#pragma unroll
    for (int ks = 0; ks < 4; ++ks) {
        wkf[ks] = cvt_h8(*(const float4*)(wkr + ks * 32), *(const float4*)(wkr + ks * 32 + 4));
        wvf[ks] = cvt_h8(*(const float4*)(wvr + ks * 32), *(const float4*)(wvr + ks * 32 + 4));
    }
    const int de = dbase + dt * 16 + quad * 4;   // epilogue d for r=0..3
    const float4 bk4 = *(const float4*)(bk + de);
    const float4 bv4 = *(const float4*)(bv + de);

    const float* xb = x + b * SEQ * DIM;

    f32x4 acc = {0.f, 0.f, 0.f, 0.f};

    for (int ch = 0; ch < 4; ++ch) {
        // ---------------- Phase A: proj-T chunk -> ldsA ----------------
#pragma unroll
        for (int nt = 0; nt < 4; ++nt) {
            const int jj16 = (nh * 4 + nt) * 16;        // j-tile base within chunk
            const int jrow = ch * 128 + jj16 + l15;     // global j for B-operand row
            const float* xr = xb + jrow * DIM + quad * 8;
            f32x4 dk = {0.f, 0.f, 0.f, 0.f};
            f32x4 dv = {0.f, 0.f, 0.f, 0.f};
#pragma unroll
            for (int ks = 0; ks < 4; ++ks) {
                const half8 xf = cvt_h8(*(const float4*)(xr + ks * 32),
                                        *(const float4*)(xr + ks * 32 + 4));
                dk = __builtin_amdgcn_mfma_f32_16x16x32_f16(wkf[ks], xf, dk, 0, 0, 0);
                dv = __builtin_amdgcn_mfma_f32_16x16x32_f16(wvf[ks], xf, dv, 0, 0, 0);
            }
            const int jj = jj16 + l15;                  // D col = lane&15
#pragma unroll
            for (int r = 0; r < 4; ++r) {
                const float e  = __expf(dk[r] + bk4[r]);
                const float vv = dv[r] + bv4[r];
                const int m0 = 2 * (dt * 16 + quad * 4 + r);   // local m
                ldsA[IDXA(m0,     jj)] = (_Float16)e;
                ldsA[IDXA(m0 + 1, jj)] = (_Float16)(e * vv);
            }
        }
        // ---------------- Phase B: exp(pos) chunk -> ldsB ----------------
        {
            const int tl = tid >> 5;              // 0..15
            const int jj = (tid & 31) * 4;        // 0..124
            const float4 p = *(const float4*)(pos + (t0 + tl) * SEQ + ch * 128 + jj);
            half4 h;
            h[0] = (_Float16)__expf(p.x); h[1] = (_Float16)__expf(p.y);
            h[2] = (_Float16)__expf(p.z); h[3] = (_Float16)__expf(p.w);
            *(half4*)&ldsA[0 - 0 + 0], (void)0;   // no-op guard (kept simple below)
            *(half4*)&ldsB[IDXB(tl, jj)] = h;
        }
        __syncthreads();
        // ---------------- Phase C: AFT accumulate ----------------
        {
            const int mrow = 16 * w + l15;        // local m row for A fragment
#pragma unroll
            for (int ks = 0; ks < 4; ++ks) {
                const int kk = ks * 32 + quad * 8;
                const half8 af = *(const half8*)&ldsA[IDXA(mrow, kk)];
                const half8 bf = *(const half8*)&ldsB[IDXB(l15, kk)];
                acc = __builtin_amdgcn_mfma_f32_16x16x32_f16(af, bf, acc, 0, 0, 0);
            }
        }
        __syncthreads();
    }

    // ---------------- Epilogue: q (f32 dot) and output ----------------
    // Wave w's AFT D-tile: rows m = 16w + quad*4 + r (local), cols t = t0 + l15.
    // m pairs: acc[0]=den(d0), acc[1]=num(d0), acc[2]=den(d0+1), acc[3]=num(d0+1)
    const int d0 = dbase + 8 * w + 2 * quad;
    const int t  = t0 + l15;
    const float* xr = xb + t * DIM;
    const float* w0 = Wq + d0 * DIM;
    const float* w1 = w0 + DIM;
    float s0 = 0.f, s1 = 0.f;
#pragma unroll
    for (int k4 = 0; k4 < 32; ++k4) {
        const float4 xv = *(const float4*)(xr + k4 * 4);
        const float4 a0 = *(const float4*)(w0 + k4 * 4);
        const float4 a1 = *(const float4*)(w1 + k4 * 4);
        s0 += xv.x * a0.x + xv.y * a0.y + xv.z * a0.z + xv.w * a0.w;
        s1 += xv.x * a1.x + xv.y * a1.y + xv.z * a1.z + xv.w * a1.w;
    }
    const float q0 = 1.f / (1.f + __expf(-(s0 + bq[d0])));
    const float q1 = 1.f / (1.f + __expf(-(s1 + bq[d0 + 1])));
    float2 o;
    o.x = q0 * acc[1] / acc[0];
    o.y = q1 * acc[3] / acc[2];
    *(float2*)(out + (b * SEQ + t) * DIM + d0) = o;
}

// ---------------------------------------------------------------------------
extern "C" void kernel_launch(void* const* d_in, const int* in_sizes, int n_in,
                              void* d_out, int out_size, void* d_ws, size_t ws_size,
                              hipStream_t stream) {
    const float* x   = (const float*)d_in[0];
    const float* Wq  = (const float*)d_in[1];
    const float* bq  = (const float*)d_in[2];
    const float* Wk  = (const float*)d_in[3];
    const float* bk  = (const float*)d_in[4];
    const float* Wv  = (const float*)d_in[5];
    const float* bv  = (const float*)d_in[6];
    const float* pos = (const float*)d_in[7];

    // Zero workspace usage: d_ws untouched (falsifies the poison-floor theory
    // if dur_us responds; wins a launch + all intermediate traffic if not).
    (void)d_ws; (void)ws_size;

    k_fused<<<256, 512, 0, stream>>>(x, Wq, bq, Wk, bk, Wv, bv, pos, (float*)d_out);
}